// Round 6
// baseline (775.579 us; speedup 1.0000x reference)
//
#include <hip/hip_runtime.h>

#define N_NODES  50000
#define N_EDGES  800000
#define D_IN     64
#define D_RADIAL 128
#define NTILES   (N_EDGES / 64)   // 12500, exact (fallback kernel)

typedef __bf16 bf16x8 __attribute__((ext_vector_type(8)));
typedef float  f32x4  __attribute__((ext_vector_type(4)));
typedef short  s16x8  __attribute__((ext_vector_type(8)));

// pack two f32 -> two bf16 (truncation) in one v_perm (MFMA inputs)
__device__ inline unsigned int pack_bf16_pair(float lo, float hi) {
    return __builtin_amdgcn_perm(__float_as_uint(hi), __float_as_uint(lo), 0x07060302u);
}

// round-to-nearest-even f32 -> bf16
__device__ inline unsigned short f2bf_rne(float f) {
    unsigned int u = __float_as_uint(f);
    u += 0x7FFFu + ((u >> 16) & 1u);
    return (unsigned short)(u >> 16);
}

// ---------------- workspace layout (CSR path) ----------------
constexpr size_t ws_align(size_t x) { return (x + 255) & ~(size_t)255; }
constexpr size_t WS_CNT  = 0;                                             // int[N_NODES]
constexpr size_t WS_OFF  = ws_align(WS_CNT  + (size_t)N_NODES * 4);       // int[N_NODES+1]
constexpr size_t WS_CUR  = ws_align(WS_OFF  + (size_t)(N_NODES + 1) * 4); // int[N_NODES]
constexpr size_t WS_BSUM = ws_align(WS_CUR  + (size_t)N_NODES * 4);       // int[128]
constexpr size_t WS_EORD = ws_align(WS_BSUM + 512);                       // int[N_EDGES] eord[pos] = edge id
constexpr size_t WS_SSRC = ws_align(WS_EORD + (size_t)N_EDGES * 4);       // int[N_EDGES] ssrc[pos] = src[eord[pos]]
constexpr size_t WS_REQUIRED = WS_SSRC + (size_t)N_EDGES * 4;             // ~13 MB

#define SCAN_B    512
#define SCAN_NBLK ((N_NODES + SCAN_B - 1) / SCAN_B)   // 98
static_assert(SCAN_NBLK <= 128, "scan_tops assumes <=128 blocks");

// ---------------- sort kernels ----------------
__global__ __launch_bounds__(256) void hist_kernel(const int* __restrict__ dst,
                                                   int* __restrict__ cnt) {
    int i = blockIdx.x * 256 + threadIdx.x;
    if (i < N_EDGES) atomicAdd(&cnt[dst[i]], 1);
}

__global__ __launch_bounds__(SCAN_B) void scan_block(const int* __restrict__ cnt,
                                                     int* __restrict__ offs,
                                                     int* __restrict__ bsum) {
    const int t = threadIdx.x, b = blockIdx.x;
    const int i = b * SCAN_B + t;
    int v = (i < N_NODES) ? cnt[i] : 0;
    __shared__ int s[SCAN_B];
    s[t] = v;
    __syncthreads();
    for (int o = 1; o < SCAN_B; o <<= 1) {
        int add = (t >= o) ? s[t - o] : 0;
        __syncthreads();
        s[t] += add;
        __syncthreads();
    }
    if (i < N_NODES) offs[i] = s[t];          // inclusive within block (temporary)
    if (t == SCAN_B - 1) bsum[b] = s[t];
}

__global__ __launch_bounds__(128) void scan_tops(int* __restrict__ bsum) {
    const int t = threadIdx.x;
    __shared__ int s[128];
    int v = (t < SCAN_NBLK) ? bsum[t] : 0;
    s[t] = v;
    __syncthreads();
    for (int o = 1; o < 128; o <<= 1) {
        int add = (t >= o) ? s[t - o] : 0;
        __syncthreads();
        s[t] += add;
        __syncthreads();
    }
    if (t < SCAN_NBLK) bsum[t] = s[t] - v;    // exclusive
}

__global__ __launch_bounds__(SCAN_B) void finalize_off(const int* __restrict__ cnt,
                                                       int* __restrict__ offs,
                                                       const int* __restrict__ bsum,
                                                       int* __restrict__ cur) {
    const int i = blockIdx.x * SCAN_B + threadIdx.x;
    if (i < N_NODES) {
        int e = offs[i] - cnt[i] + bsum[blockIdx.x];   // global exclusive prefix
        offs[i] = e;
        cur[i]  = e;
    }
    if (i == 0) offs[N_NODES] = N_EDGES;
}

// build dst-sorted edge list: eord[pos] = edge id, ssrc[pos] = src of that edge
__global__ __launch_bounds__(256) void scatter_build(const int* __restrict__ dst,
                                                     const int* __restrict__ src,
                                                     int* __restrict__ cur,
                                                     int* __restrict__ eord,
                                                     int* __restrict__ ssrc) {
    int i = blockIdx.x * 256 + threadIdx.x;
    if (i < N_EDGES) {
        int pos = atomicAdd(&cur[dst[i]], 1);
        eord[pos] = i;
        ssrc[pos] = src[i];
    }
}

// ---------------- fused node-centric kernel: one wave owns one node ----------------
// Per node: iterate its dst-sorted edge run in 16-row MFMA tiles; multiply each
// filter row by x[src] in registers; sum rows (uniform shfl reduce); ONE plain
// store per output element. No atomics, no intermediate msg buffer.
__global__ __launch_bounds__(256) void node_kernel(
    const float* __restrict__ x,        // [N, 64]
    const float* __restrict__ eb,       // [E, 128]
    const int*   __restrict__ eord,     // [E] dst-sorted -> edge id
    const int*   __restrict__ ssrc,     // [E] dst-sorted -> src node
    const int*   __restrict__ offs,     // [N+1]
    const float* __restrict__ W,        // [64, 128]
    const float* __restrict__ bias_p,   // [64]
    float*       __restrict__ out)      // [N, 64]
{
    const int lane = threadIdx.x & 63;
    const int wv   = threadIdx.x >> 6;
    const int l15  = lane & 15;
    const int quad = lane >> 4;

    // B-operand fragments of W' (W'[r][d] = W[d][r]); loaded once per block
    bf16x8 wfrag[4][4];
    #pragma unroll
    for (int nt = 0; nt < 4; ++nt) {
        const int d = nt * 16 + l15;
        #pragma unroll
        for (int kt = 0; kt < 4; ++kt) {
            const float* p = W + d * D_RADIAL + kt * 32 + quad * 8;
            s16x8 s;
            #pragma unroll
            for (int j = 0; j < 8; ++j) s[j] = (short)f2bf_rne(p[j]);
            wfrag[nt][kt] = __builtin_bit_cast(bf16x8, s);
        }
    }
    float bv[4];
    #pragma unroll
    for (int nt = 0; nt < 4; ++nt) bv[nt] = bias_p[nt * 16 + l15];

    const int wid = blockIdx.x * 4 + wv;
    const int nw  = gridDim.x * 4;
    for (int n = wid; n < N_NODES; n += nw) {
        const int j0 = offs[n], j1 = offs[n + 1];

        float nacc[4] = {0.f, 0.f, 0.f, 0.f};   // this lane's 4 output cols (nt*16+l15)

        for (int p0 = j0; p0 < j1; p0 += 16) {
            // A-frag rows: sorted positions p0+l15 (l15-dependent validity)
            const int  pA = p0 + l15;
            const bool av = (pA < j1);
            const int  e  = eord[av ? pA : (j1 - 1)];

            f32x4 acc[4];
            #pragma unroll
            for (int nt = 0; nt < 4; ++nt) acc[nt] = (f32x4){0.f, 0.f, 0.f, 0.f};

            #pragma unroll
            for (int kt = 0; kt < 4; ++kt) {
                bf16x8 afrag;
                if (av) {
                    const float* p = eb + (long)e * D_RADIAL + kt * 32 + quad * 8;
                    f32x4 a0 = *(const f32x4*)(p);
                    f32x4 a1 = *(const f32x4*)(p + 4);
                    int4 packed;
                    packed.x = pack_bf16_pair(a0[0], a0[1]);
                    packed.y = pack_bf16_pair(a0[2], a0[3]);
                    packed.z = pack_bf16_pair(a1[0], a1[1]);
                    packed.w = pack_bf16_pair(a1[2], a1[3]);
                    afrag = __builtin_bit_cast(bf16x8, packed);
                } else {
                    afrag = __builtin_bit_cast(bf16x8, (int4){0, 0, 0, 0});
                }
                #pragma unroll
                for (int nt = 0; nt < 4; ++nt)
                    acc[nt] = __builtin_amdgcn_mfma_f32_16x16x32_bf16(
                        afrag, wfrag[nt][kt], acc[nt], 0, 0, 0);
            }

            // epilogue: D[row=quad*4+reg][col=l15]; row <-> sorted position p0+row.
            // multiply by x[src] per row, accumulate this lane's 4 rows into nacc.
            #pragma unroll
            for (int reg = 0; reg < 4; ++reg) {
                const int  row = quad * 4 + reg;
                const int  pos = p0 + row;
                const bool rv  = (pos < j1);
                const int  s   = ssrc[rv ? pos : (j1 - 1)];
                const float* xrow = x + (long)s * D_IN;
                #pragma unroll
                for (int nt = 0; nt < 4; ++nt) {
                    const float xv  = xrow[nt * 16 + l15];
                    const float val = (acc[nt][reg] + bv[nt]) * xv;
                    nacc[nt] += rv ? val : 0.f;
                }
            }
        }

        // uniform cross-quad reduction (no segments: whole tile belongs to node n)
        #pragma unroll
        for (int nt = 0; nt < 4; ++nt) {
            nacc[nt] += __shfl_xor(nacc[nt], 16, 64);
            nacc[nt] += __shfl_xor(nacc[nt], 32, 64);
        }
        if (quad == 0) {
            float* orow = out + (size_t)n * D_IN;
            #pragma unroll
            for (int nt = 0; nt < 4; ++nt)
                orow[nt * 16 + l15] = nacc[nt];
        }
    }
}

// ---------------- legacy fallback (atomic) kernel — unchanged ----------------
__global__ __launch_bounds__(256) void edge_msg_kernel(
    const float* __restrict__ x,
    const float* __restrict__ eb,
    const int*   __restrict__ src,
    const int*   __restrict__ dst,
    const float* __restrict__ W,
    const float* __restrict__ bias_p,
    float*       __restrict__ out)
{
    const int lane = threadIdx.x & 63;
    const int wv   = threadIdx.x >> 6;
    const int l15  = lane & 15;
    const int quad = lane >> 4;

    bf16x8 wfrag[4][4];
    #pragma unroll
    for (int nt = 0; nt < 4; ++nt) {
        const int d = nt * 16 + l15;
        #pragma unroll
        for (int kt = 0; kt < 4; ++kt) {
            const float* p = W + d * D_RADIAL + kt * 32 + quad * 8;
            s16x8 s;
            #pragma unroll
            for (int j = 0; j < 8; ++j) s[j] = (short)f2bf_rne(p[j]);
            wfrag[nt][kt] = __builtin_bit_cast(bf16x8, s);
        }
    }
    float bv[4];
    #pragma unroll
    for (int nt = 0; nt < 4; ++nt) bv[nt] = bias_p[nt * 16 + l15];

    for (int tile = blockIdx.x; tile < NTILES; tile += gridDim.x) {
        const int ebase = tile * 64 + wv * 16;

        f32x4 acc[4];
        #pragma unroll
        for (int nt = 0; nt < 4; ++nt) acc[nt] = (f32x4){0.f, 0.f, 0.f, 0.f};

        #pragma unroll
        for (int kt = 0; kt < 4; ++kt) {
            const float* p = eb + (long)(ebase + l15) * D_RADIAL + kt * 32 + quad * 8;
            f32x4 a0 = *(const f32x4*)(p);
            f32x4 a1 = *(const f32x4*)(p + 4);
            int4 packed;
            packed.x = pack_bf16_pair(a0[0], a0[1]);
            packed.y = pack_bf16_pair(a0[2], a0[3]);
            packed.z = pack_bf16_pair(a1[0], a1[1]);
            packed.w = pack_bf16_pair(a1[2], a1[3]);
            bf16x8 afrag = __builtin_bit_cast(bf16x8, packed);
            #pragma unroll
            for (int nt = 0; nt < 4; ++nt)
                acc[nt] = __builtin_amdgcn_mfma_f32_16x16x32_bf16(
                    afrag, wfrag[nt][kt], acc[nt], 0, 0, 0);
        }

        const int erow = ebase + quad * 4;
        #pragma unroll
        for (int reg = 0; reg < 4; ++reg) {
            const int e  = erow + reg;
            const int sv = src[e];
            const int dv = dst[e];
            const float* xrow = x   + (long)sv * D_IN;
            float*       orow = out + (long)dv * D_IN;
            #pragma unroll
            for (int nt = 0; nt < 4; ++nt) {
                const int d = nt * 16 + l15;
                const float val = (acc[nt][reg] + bv[nt]) * xrow[d];
                unsafeAtomicAdd(orow + d, val);
            }
        }
    }
}

extern "C" void kernel_launch(void* const* d_in, const int* in_sizes, int n_in,
                              void* d_out, int out_size, void* d_ws, size_t ws_size,
                              hipStream_t stream) {
    const float* x    = (const float*)d_in[0];
    const float* eb   = (const float*)d_in[1];
    const int*   src  = (const int*)d_in[2];
    const int*   dst  = (const int*)d_in[3];
    const float* W    = (const float*)d_in[4];
    const float* bias = (const float*)d_in[5];
    float* out = (float*)d_out;

    if (ws_size >= WS_REQUIRED) {
        // CSR fused path: sort edges by dst, then one node-centric MFMA kernel.
        // No float atomics, no intermediate message buffer.
        char* ws   = (char*)d_ws;
        int*  cnt  = (int*)(ws + WS_CNT);
        int*  offs = (int*)(ws + WS_OFF);
        int*  cur  = (int*)(ws + WS_CUR);
        int*  bsum = (int*)(ws + WS_BSUM);
        int*  eord = (int*)(ws + WS_EORD);
        int*  ssrc = (int*)(ws + WS_SSRC);

        hipMemsetAsync(cnt, 0, (size_t)N_NODES * 4, stream);
        hist_kernel   <<<(N_EDGES + 255) / 256, 256, 0, stream>>>(dst, cnt);
        scan_block    <<<SCAN_NBLK, SCAN_B, 0, stream>>>(cnt, offs, bsum);
        scan_tops     <<<1, 128, 0, stream>>>(bsum);
        finalize_off  <<<SCAN_NBLK, SCAN_B, 0, stream>>>(cnt, offs, bsum, cur);
        scatter_build <<<(N_EDGES + 255) / 256, 256, 0, stream>>>(dst, src, cur, eord, ssrc);
        // node_kernel writes every output element -> no d_out memset needed
        node_kernel   <<<1280, 256, 0, stream>>>(x, eb, eord, ssrc, offs, W, bias, out);
    } else {
        // fallback: original atomic kernel (harness poisons d_out -> zero it first)
        hipMemsetAsync(d_out, 0, (size_t)N_NODES * D_IN * sizeof(float), stream);
        edge_msg_kernel<<<1024, 256, 0, stream>>>(x, eb, src, dst, W, bias, out);
    }
}

// Round 11
// 688.873 us; speedup vs baseline: 1.1259x; 1.1259x over previous
//
#include <hip/hip_runtime.h>

#define N_NODES  50000
#define N_EDGES  800000
#define D_IN     64
#define D_RADIAL 128
#define NTILES   (N_EDGES / 64)   // 12500, exact (fallback kernel)

typedef __bf16 bf16x8 __attribute__((ext_vector_type(8)));
typedef float  f32x4  __attribute__((ext_vector_type(4)));
typedef short  s16x8  __attribute__((ext_vector_type(8)));

// pack two f32 -> two bf16 (truncation) in one v_perm (MFMA inputs)
__device__ inline unsigned int pack_bf16_pair(float lo, float hi) {
    return __builtin_amdgcn_perm(__float_as_uint(hi), __float_as_uint(lo), 0x07060302u);
}

// round-to-nearest-even f32 -> bf16
__device__ inline unsigned short f2bf_rne(float f) {
    unsigned int u = __float_as_uint(f);
    u += 0x7FFFu + ((u >> 16) & 1u);
    return (unsigned short)(u >> 16);
}

__device__ inline int mini(int a, int b) { return a < b ? a : b; }

// ---------------- workspace layout (CSR path) ----------------
constexpr size_t ws_align(size_t x) { return (x + 255) & ~(size_t)255; }
constexpr size_t WS_CNT  = 0;                                             // int[N_NODES]
constexpr size_t WS_OFF  = ws_align(WS_CNT  + (size_t)N_NODES * 4);       // int[N_NODES+1]
constexpr size_t WS_CUR  = ws_align(WS_OFF  + (size_t)(N_NODES + 1) * 4); // int[N_NODES]
constexpr size_t WS_BSUM = ws_align(WS_CUR  + (size_t)N_NODES * 4);       // int[128]
constexpr size_t WS_EORD = ws_align(WS_BSUM + 512);                       // int[N_EDGES] eord[pos] = edge id
constexpr size_t WS_SSRC = ws_align(WS_EORD + (size_t)N_EDGES * 4);       // int[N_EDGES] ssrc[pos] = src[eord[pos]]
constexpr size_t WS_REQUIRED = WS_SSRC + (size_t)N_EDGES * 4;             // ~13 MB

#define SCAN_B    512
#define SCAN_NBLK ((N_NODES + SCAN_B - 1) / SCAN_B)   // 98
static_assert(SCAN_NBLK <= 128, "scan_tops assumes <=128 blocks");

// ---------------- sort kernels ----------------
__global__ __launch_bounds__(256) void hist_kernel(const int* __restrict__ dst,
                                                   int* __restrict__ cnt) {
    int i = blockIdx.x * 256 + threadIdx.x;
    if (i < N_EDGES) atomicAdd(&cnt[dst[i]], 1);
}

__global__ __launch_bounds__(SCAN_B) void scan_block(const int* __restrict__ cnt,
                                                     int* __restrict__ offs,
                                                     int* __restrict__ bsum) {
    const int t = threadIdx.x, b = blockIdx.x;
    const int i = b * SCAN_B + t;
    int v = (i < N_NODES) ? cnt[i] : 0;
    __shared__ int s[SCAN_B];
    s[t] = v;
    __syncthreads();
    for (int o = 1; o < SCAN_B; o <<= 1) {
        int add = (t >= o) ? s[t - o] : 0;
        __syncthreads();
        s[t] += add;
        __syncthreads();
    }
    if (i < N_NODES) offs[i] = s[t];          // inclusive within block (temporary)
    if (t == SCAN_B - 1) bsum[b] = s[t];
}

__global__ __launch_bounds__(128) void scan_tops(int* __restrict__ bsum) {
    const int t = threadIdx.x;
    __shared__ int s[128];
    int v = (t < SCAN_NBLK) ? bsum[t] : 0;
    s[t] = v;
    __syncthreads();
    for (int o = 1; o < 128; o <<= 1) {
        int add = (t >= o) ? s[t - o] : 0;
        __syncthreads();
        s[t] += add;
        __syncthreads();
    }
    if (t < SCAN_NBLK) bsum[t] = s[t] - v;    // exclusive
}

__global__ __launch_bounds__(SCAN_B) void finalize_off(const int* __restrict__ cnt,
                                                       int* __restrict__ offs,
                                                       const int* __restrict__ bsum,
                                                       int* __restrict__ cur) {
    const int i = blockIdx.x * SCAN_B + threadIdx.x;
    if (i < N_NODES) {
        int e = offs[i] - cnt[i] + bsum[blockIdx.x];   // global exclusive prefix
        offs[i] = e;
        cur[i]  = e;
    }
    if (i == 0) offs[N_NODES] = N_EDGES;
}

// build dst-sorted edge list: eord[pos] = edge id, ssrc[pos] = src of that edge
__global__ __launch_bounds__(256) void scatter_build(const int* __restrict__ dst,
                                                     const int* __restrict__ src,
                                                     int* __restrict__ cur,
                                                     int* __restrict__ eord,
                                                     int* __restrict__ ssrc) {
    int i = blockIdx.x * 256 + threadIdx.x;
    if (i < N_EDGES) {
        int pos = atomicAdd(&cur[dst[i]], 1);
        eord[pos] = i;
        ssrc[pos] = src[i];
    }
}

// ---------------- fused node-centric kernel: one wave owns one node ----------------
// ALL loads unconditional (index-clamped to j1-1); invalid rows masked only in
// the epilogue accumulate. This lets the compiler batch-issue the whole tile's
// loads (eord, ssrc, 8x eb, 16x x) instead of serializing behind exec-mask
// branches — round 6 measured ~1.3 outstanding loads/wave from exactly that.
__global__ __launch_bounds__(256) void node_kernel(
    const float* __restrict__ x,        // [N, 64]
    const float* __restrict__ eb,       // [E, 128]
    const int*   __restrict__ eord,     // [E] dst-sorted -> edge id
    const int*   __restrict__ ssrc,     // [E] dst-sorted -> src node
    const int*   __restrict__ offs,     // [N+1]
    const float* __restrict__ W,        // [64, 128]
    const float* __restrict__ bias_p,   // [64]
    float*       __restrict__ out)      // [N, 64]
{
    const int lane = threadIdx.x & 63;
    const int wv   = threadIdx.x >> 6;
    const int l15  = lane & 15;
    const int quad = lane >> 4;

    // B-operand fragments of W' (W'[r][d] = W[d][r]); loaded once per block
    bf16x8 wfrag[4][4];
    #pragma unroll
    for (int nt = 0; nt < 4; ++nt) {
        const int d = nt * 16 + l15;
        #pragma unroll
        for (int kt = 0; kt < 4; ++kt) {
            const float* p = W + d * D_RADIAL + kt * 32 + quad * 8;
            s16x8 s;
            #pragma unroll
            for (int j = 0; j < 8; ++j) s[j] = (short)f2bf_rne(p[j]);
            wfrag[nt][kt] = __builtin_bit_cast(bf16x8, s);
        }
    }
    float bv[4];
    #pragma unroll
    for (int nt = 0; nt < 4; ++nt) bv[nt] = bias_p[nt * 16 + l15];

    const int wid = blockIdx.x * 4 + wv;
    const int nw  = gridDim.x * 4;
    for (int n = wid; n < N_NODES; n += nw) {
        const int j0 = offs[n], j1 = offs[n + 1];

        float nacc[4] = {0.f, 0.f, 0.f, 0.f};   // this lane's 4 output cols (nt*16+l15)

        for (int p0 = j0; p0 < j1; p0 += 16) {
            const int last = j1 - 1;

            // --- index loads (two independent chains), unconditional ---
            const int e = eord[mini(p0 + l15, last)];          // A-side row for lane group l15
            int sr[4];
            #pragma unroll
            for (int reg = 0; reg < 4; ++reg)
                sr[reg] = ssrc[mini(p0 + quad * 4 + reg, last)];

            // --- x gather hoisted above the MFMA (independent of eb chain) ---
            float xv[4][4];
            #pragma unroll
            for (int reg = 0; reg < 4; ++reg) {
                const float* xrow = x + (long)sr[reg] * D_IN;
                #pragma unroll
                for (int nt = 0; nt < 4; ++nt)
                    xv[reg][nt] = xrow[nt * 16 + l15];
            }

            // --- eb loads + MFMA; loads are branch-free so the compiler can
            //     hoist all 8 dwordx4 ahead of the first MFMA ---
            f32x4 acc[4];
            #pragma unroll
            for (int nt = 0; nt < 4; ++nt) acc[nt] = (f32x4){0.f, 0.f, 0.f, 0.f};

            const float* pbase = eb + (long)e * D_RADIAL + quad * 8;
            #pragma unroll
            for (int kt = 0; kt < 4; ++kt) {
                f32x4 a0 = *(const f32x4*)(pbase + kt * 32);
                f32x4 a1 = *(const f32x4*)(pbase + kt * 32 + 4);
                int4 packed;
                packed.x = pack_bf16_pair(a0[0], a0[1]);
                packed.y = pack_bf16_pair(a0[2], a0[3]);
                packed.z = pack_bf16_pair(a1[0], a1[1]);
                packed.w = pack_bf16_pair(a1[2], a1[3]);
                bf16x8 afrag = __builtin_bit_cast(bf16x8, packed);
                #pragma unroll
                for (int nt = 0; nt < 4; ++nt)
                    acc[nt] = __builtin_amdgcn_mfma_f32_16x16x32_bf16(
                        afrag, wfrag[nt][kt], acc[nt], 0, 0, 0);
            }

            // --- epilogue: D[row=quad*4+reg][col=l15]; clamped rows masked here ---
            #pragma unroll
            for (int reg = 0; reg < 4; ++reg) {
                const bool rv = (p0 + quad * 4 + reg) < j1;
                #pragma unroll
                for (int nt = 0; nt < 4; ++nt) {
                    const float val = (acc[nt][reg] + bv[nt]) * xv[reg][nt];
                    nacc[nt] += rv ? val : 0.f;
                }
            }
        }

        // uniform cross-quad reduction (whole tile belongs to node n)
        #pragma unroll
        for (int nt = 0; nt < 4; ++nt) {
            nacc[nt] += __shfl_xor(nacc[nt], 16, 64);
            nacc[nt] += __shfl_xor(nacc[nt], 32, 64);
        }
        if (quad == 0) {
            float* orow = out + (size_t)n * D_IN;
            #pragma unroll
            for (int nt = 0; nt < 4; ++nt)
                orow[nt * 16 + l15] = nacc[nt];
        }
    }
}

// ---------------- legacy fallback (atomic) kernel — unchanged ----------------
__global__ __launch_bounds__(256) void edge_msg_kernel(
    const float* __restrict__ x,
    const float* __restrict__ eb,
    const int*   __restrict__ src,
    const int*   __restrict__ dst,
    const float* __restrict__ W,
    const float* __restrict__ bias_p,
    float*       __restrict__ out)
{
    const int lane = threadIdx.x & 63;
    const int wv   = threadIdx.x >> 6;
    const int l15  = lane & 15;
    const int quad = lane >> 4;

    bf16x8 wfrag[4][4];
    #pragma unroll
    for (int nt = 0; nt < 4; ++nt) {
        const int d = nt * 16 + l15;
        #pragma unroll
        for (int kt = 0; kt < 4; ++kt) {
            const float* p = W + d * D_RADIAL + kt * 32 + quad * 8;
            s16x8 s;
            #pragma unroll
            for (int j = 0; j < 8; ++j) s[j] = (short)f2bf_rne(p[j]);
            wfrag[nt][kt] = __builtin_bit_cast(bf16x8, s);
        }
    }
    float bv[4];
    #pragma unroll
    for (int nt = 0; nt < 4; ++nt) bv[nt] = bias_p[nt * 16 + l15];

    for (int tile = blockIdx.x; tile < NTILES; tile += gridDim.x) {
        const int ebase = tile * 64 + wv * 16;

        f32x4 acc[4];
        #pragma unroll
        for (int nt = 0; nt < 4; ++nt) acc[nt] = (f32x4){0.f, 0.f, 0.f, 0.f};

        #pragma unroll
        for (int kt = 0; kt < 4; ++kt) {
            const float* p = eb + (long)(ebase + l15) * D_RADIAL + kt * 32 + quad * 8;
            f32x4 a0 = *(const f32x4*)(p);
            f32x4 a1 = *(const f32x4*)(p + 4);
            int4 packed;
            packed.x = pack_bf16_pair(a0[0], a0[1]);
            packed.y = pack_bf16_pair(a0[2], a0[3]);
            packed.z = pack_bf16_pair(a1[0], a1[1]);
            packed.w = pack_bf16_pair(a1[2], a1[3]);
            bf16x8 afrag = __builtin_bit_cast(bf16x8, packed);
            #pragma unroll
            for (int nt = 0; nt < 4; ++nt)
                acc[nt] = __builtin_amdgcn_mfma_f32_16x16x32_bf16(
                    afrag, wfrag[nt][kt], acc[nt], 0, 0, 0);
        }

        const int erow = ebase + quad * 4;
        #pragma unroll
        for (int reg = 0; reg < 4; ++reg) {
            const int e  = erow + reg;
            const int sv = src[e];
            const int dv = dst[e];
            const float* xrow = x   + (long)sv * D_IN;
            float*       orow = out + (long)dv * D_IN;
            #pragma unroll
            for (int nt = 0; nt < 4; ++nt) {
                const int d = nt * 16 + l15;
                const float val = (acc[nt][reg] + bv[nt]) * xrow[d];
                unsafeAtomicAdd(orow + d, val);
            }
        }
    }
}

extern "C" void kernel_launch(void* const* d_in, const int* in_sizes, int n_in,
                              void* d_out, int out_size, void* d_ws, size_t ws_size,
                              hipStream_t stream) {
    const float* x    = (const float*)d_in[0];
    const float* eb   = (const float*)d_in[1];
    const int*   src  = (const int*)d_in[2];
    const int*   dst  = (const int*)d_in[3];
    const float* W    = (const float*)d_in[4];
    const float* bias = (const float*)d_in[5];
    float* out = (float*)d_out;

    if (ws_size >= WS_REQUIRED) {
        // CSR fused path: sort edges by dst, then one node-centric MFMA kernel.
        // No float atomics, no intermediate message buffer.
        char* ws   = (char*)d_ws;
        int*  cnt  = (int*)(ws + WS_CNT);
        int*  offs = (int*)(ws + WS_OFF);
        int*  cur  = (int*)(ws + WS_CUR);
        int*  bsum = (int*)(ws + WS_BSUM);
        int*  eord = (int*)(ws + WS_EORD);
        int*  ssrc = (int*)(ws + WS_SSRC);

        hipMemsetAsync(cnt, 0, (size_t)N_NODES * 4, stream);
        hist_kernel   <<<(N_EDGES + 255) / 256, 256, 0, stream>>>(dst, cnt);
        scan_block    <<<SCAN_NBLK, SCAN_B, 0, stream>>>(cnt, offs, bsum);
        scan_tops     <<<1, 128, 0, stream>>>(bsum);
        finalize_off  <<<SCAN_NBLK, SCAN_B, 0, stream>>>(cnt, offs, bsum, cur);
        scatter_build <<<(N_EDGES + 255) / 256, 256, 0, stream>>>(dst, src, cur, eord, ssrc);
        // node_kernel writes every output element -> no d_out memset needed
        node_kernel   <<<2560, 256, 0, stream>>>(x, eb, eord, ssrc, offs, W, bias, out);
    } else {
        // fallback: original atomic kernel (harness poisons d_out -> zero it first)
        hipMemsetAsync(d_out, 0, (size_t)N_NODES * D_IN * sizeof(float), stream);
        edge_msg_kernel<<<1024, 256, 0, stream>>>(x, eb, src, dst, W, bias, out);
    }
}